// Round 5
// baseline (119.947 us; speedup 1.0000x reference)
//
#include <hip/hip_runtime.h>

// SpectralConv2D: out[f,row,col,q] = relu( sum_{k=0..8} Lambda[phi] * Yflat[phi*128+q] )
// phi = (3*row+block)*378 + (3*col+j);  Yflat is flattened (C=128,R=378,S=378) with
// Y[c,r,s] = raw[c*16384 + (r/3+r%3)*128 + (s/3+s%3)];  broadcast over f=0..63.
//
// Two-pass: (1) compute the 8.13MB plane into out[filter 0] with cached stores;
// (2) broadcast plane 0 -> planes 1..63 with register-staged nontemporal streams.

#define L_TOT    15876            // 126*126
#define PLANE_F4 (L_TOT * 32)     // f4 per filter plane = 2,032,128
#define CHUNK_F4 1024             // f4 per pass-2 block (16KB)

typedef float f4 __attribute__((ext_vector_type(4)));

__global__ __launch_bounds__(256) void spectral_compute(
    const float* __restrict__ x, const float* __restrict__ lam,
    float* __restrict__ out)
{
    const int t = threadIdx.x;
    const int l = blockIdx.x * 2 + (t >> 7);
    const int q = t & 127;
    const int row = l / 126;
    const int col = l - row * 126;

    float acc = 0.0f;
#pragma unroll
    for (int b3 = 0; b3 < 3; ++b3) {
#pragma unroll
        for (int j = 0; j < 3; ++j) {
            const unsigned phi = (unsigned)((3 * row + b3) * 378 + 3 * col + j);
            const unsigned n   = phi * 128u + (unsigned)q;  // fits u32
            const unsigned c   = n / 142884u;               // 378*378
            const unsigned rem = n - c * 142884u;
            const unsigned r   = rem / 378u;
            const unsigned ss  = rem - r * 378u;
            const unsigned src = c * 16384u + (r / 3u + r % 3u) * 128u + (ss / 3u + ss % 3u);
            acc = fmaf(x[src], lam[phi], acc);
        }
    }
    out[(size_t)l * 128 + q] = fmaxf(acc, 0.0f);  // filter-0 plane, cached store
}

__global__ __launch_bounds__(256) void spectral_bcast(float* __restrict__ out)
{
    const int t = threadIdx.x;
    const size_t cbase = (size_t)blockIdx.x * CHUNK_F4;
    const f4* p0 = (const f4*)out;
    f4* o4 = (f4*)out;

    f4  v[4];
    bool ok[4];
    int idx[4];
#pragma unroll
    for (int k = 0; k < 4; ++k) {
        idx[k] = t + k * 256;
        ok[k]  = (cbase + (size_t)idx[k]) < (size_t)PLANE_F4;
        v[k]   = ok[k] ? p0[cbase + idx[k]] : (f4){0.f, 0.f, 0.f, 0.f};
    }

    int ff = 1 + (int)(blockIdx.x % 63u);   // rotate starting plane per block
#pragma unroll 1
    for (int j = 0; j < 63; ++j) {
        f4* dst = o4 + (size_t)ff * PLANE_F4 + cbase;
#pragma unroll
        for (int k = 0; k < 4; ++k)
            if (ok[k]) __builtin_nontemporal_store(v[k], &dst[idx[k]]);
        ++ff;
        if (ff == 64) ff = 1;
    }
}

extern "C" void kernel_launch(void* const* d_in, const int* in_sizes, int n_in,
                              void* d_out, int out_size, void* d_ws, size_t ws_size,
                              hipStream_t stream) {
    const float* x   = (const float*)d_in[0];   // (1,128,128,128) f32
    const float* lam = (const float*)d_in[1];   // (1, 142884) f32
    float* out = (float*)d_out;                 // (64,126,126,128) f32

    spectral_compute<<<L_TOT / 2, 256, 0, stream>>>(x, lam, out);
    const int nblocks = (PLANE_F4 + CHUNK_F4 - 1) / CHUNK_F4;   // 1985
    spectral_bcast<<<nblocks, 256, 0, stream>>>(out);
}